// Round 2
// baseline (1092.927 us; speedup 1.0000x reference)
//
#include <hip/hip_runtime.h>
#include <cstdint>
#include <cstddef>

typedef __attribute__((ext_vector_type(8))) short short8;
typedef __attribute__((ext_vector_type(4))) short short4v;
typedef __attribute__((ext_vector_type(4))) float float4v;
typedef __attribute__((ext_vector_type(4))) int int4v;
typedef unsigned short ushort_t;

__device__ __forceinline__ ushort_t f2bf(float f) {
  unsigned u = __builtin_bit_cast(unsigned, f);
  u = (u + 0x7FFFu + ((u >> 16) & 1u)) >> 16;  // RNE
  return (ushort_t)u;
}
__device__ __forceinline__ float bf2f(ushort_t h) {
  unsigned u = ((unsigned)h) << 16;
  return __builtin_bit_cast(float, u);
}

__device__ __forceinline__ void gld_lds16(const void* g, void* l) {
  __builtin_amdgcn_global_load_lds(
      (const __attribute__((address_space(1))) void*)g,
      (__attribute__((address_space(3))) void*)l, 16, 0, 0);
}

// ---------------------------------------------------------------------------
// TN GEMM with atomic split-K: P[m][n] += sum_k A[m][k]*B[n][k].
// A:[M][K] bf16, B:[N][K] bf16, P fp32 [M][N] pre-zeroed.
// Tile 128x128, BK=64, grid (M/128, N/128, S), block 256.
// ---------------------------------------------------------------------------
__global__ __launch_bounds__(256, 2) void gemm_tn(
    const ushort_t* __restrict__ A, const ushort_t* __restrict__ B,
    float* __restrict__ P, int M, int N, int K, int kslice) {
  __shared__ ushort_t As[128 * 64];
  __shared__ ushort_t Bs[128 * 64];
  const int tid = threadIdx.x;
  const int lane = tid & 63;
  const int wave = tid >> 6;
  const int wm = (wave & 1) * 64;
  const int wn = (wave >> 1) * 64;
  const int m0 = blockIdx.x * 128;
  const int n0 = blockIdx.y * 128;
  const int k0 = blockIdx.z * kslice;

  float4v acc[4][4] = {};

  for (int kt = 0; kt < kslice; kt += 64) {
    const ushort_t* Ag = A + (size_t)m0 * K + (k0 + kt);
    const ushort_t* Bg = B + (size_t)n0 * K + (k0 + kt);
#pragma unroll
    for (int i = 0; i < 4; i++) {
      int f = i * 4096 + tid * 16;  // flat byte in 16KB tile
      int r = f >> 7;               // row (128B per row = 64 bf16)
      int cb = f & 127;             // byte within row
      gld_lds16((const char*)(Ag + (size_t)r * K) + cb, (char*)As + f);
      gld_lds16((const char*)(Bg + (size_t)r * K) + cb, (char*)Bs + f);
    }
    __syncthreads();
#pragma unroll
    for (int ks = 0; ks < 64; ks += 32) {
      short8 af[4], bfr[4];
      const int kr = ks + (lane >> 4) * 8;
      const int l15 = lane & 15;
#pragma unroll
      for (int im = 0; im < 4; im++)
        af[im] = *(const short8*)&As[(wm + im * 16 + l15) * 64 + kr];
#pragma unroll
      for (int in = 0; in < 4; in++)
        bfr[in] = *(const short8*)&Bs[(wn + in * 16 + l15) * 64 + kr];
#pragma unroll
      for (int im = 0; im < 4; im++)
#pragma unroll
        for (int in = 0; in < 4; in++)
          acc[im][in] = __builtin_amdgcn_mfma_f32_16x16x32_bf16(
              af[im], bfr[in], acc[im][in], 0, 0, 0);
    }
    __syncthreads();
  }
  // C/D layout: col(n) = lane&15, row(m) = (lane>>4)*4 + reg  [m89/m91]
  const int cn = lane & 15;
  const int cr = (lane >> 4) * 4;
#pragma unroll
  for (int im = 0; im < 4; im++)
#pragma unroll
    for (int in = 0; in < 4; in++)
#pragma unroll
      for (int r = 0; r < 4; r++) {
        int m = wm + im * 16 + cr + r;
        int n = wn + in * 16 + cn;
        unsafeAtomicAdd(&P[(size_t)(m0 + m) * N + (n0 + n)], acc[im][in][r]);
      }
}

// ---------------------------------------------------------------------------
// fp32 [R][C] -> bf16 transposed [C][R] (+ optional non-transposed copy).
// bf16 conversion BEFORE the LDS round-trip; nontemporal fp32 loads.
// tile 64x64, 256 threads.
// ---------------------------------------------------------------------------
__global__ __launch_bounds__(256) void dualcast_f32_k(
    const float* __restrict__ src, ushort_t* __restrict__ dstN,
    ushort_t* __restrict__ dstT, int R, int C) {
  __shared__ ushort_t tile[64][72];  // stride 72 elems = 144 B (16B-aligned)
  const int r0 = blockIdx.x * 64, c0 = blockIdx.y * 64;
  const int tr = threadIdx.x >> 2, cs = (threadIdx.x & 3) * 16;
  const float* s = src + (size_t)(r0 + tr) * C + c0 + cs;
  ushort_t v[16];
#pragma unroll
  for (int j = 0; j < 16; j += 4) {
    float4v t4 = __builtin_nontemporal_load((const float4v*)(s + j));
    v[j] = f2bf(t4.x); v[j + 1] = f2bf(t4.y);
    v[j + 2] = f2bf(t4.z); v[j + 3] = f2bf(t4.w);
  }
  if (dstN) {
    ushort_t* d = dstN + (size_t)(r0 + tr) * C + c0 + cs;
    *(short8*)d = *(const short8*)&v[0];
    *(short8*)(d + 8) = *(const short8*)&v[8];
  }
  *(short8*)&tile[tr][cs] = *(const short8*)&v[0];
  *(short8*)&tile[tr][cs + 8] = *(const short8*)&v[8];
  __syncthreads();
  const int tc = threadIdx.x >> 2, rs = (threadIdx.x & 3) * 16;
  ushort_t o[16];
#pragma unroll
  for (int j = 0; j < 16; j++) o[j] = tile[rs + j][tc];
  ushort_t* d = dstT + (size_t)(c0 + tc) * R + r0 + rs;
  *(short8*)d = *(const short8*)&o[0];
  *(short8*)(d + 8) = *(const short8*)&o[8];
}

// int32 [R][C] -> bf16 (x>0 ? 1 : 0) transposed [C][R]
__global__ __launch_bounds__(256) void tcast_i32_k(
    const int* __restrict__ src, ushort_t* __restrict__ dstT, int R, int C) {
  __shared__ ushort_t tile[64][72];
  const int r0 = blockIdx.x * 64, c0 = blockIdx.y * 64;
  const int tr = threadIdx.x >> 2, cs = (threadIdx.x & 3) * 16;
  const int* s = src + (size_t)(r0 + tr) * C + c0 + cs;
  const ushort_t one = 0x3F80, zero = 0;
  ushort_t v[16];
#pragma unroll
  for (int j = 0; j < 16; j += 4) {
    int4v t4 = __builtin_nontemporal_load((const int4v*)(s + j));
    v[j] = t4.x > 0 ? one : zero;
    v[j + 1] = t4.y > 0 ? one : zero;
    v[j + 2] = t4.z > 0 ? one : zero;
    v[j + 3] = t4.w > 0 ? one : zero;
  }
  *(short8*)&tile[tr][cs] = *(const short8*)&v[0];
  *(short8*)&tile[tr][cs + 8] = *(const short8*)&v[8];
  __syncthreads();
  const int tc = threadIdx.x >> 2, rs = (threadIdx.x & 3) * 16;
  ushort_t o[16];
#pragma unroll
  for (int j = 0; j < 16; j++) o[j] = tile[rs + j][tc];
  ushort_t* d = dstT + (size_t)(c0 + tc) * R + r0 + rs;
  *(short8*)d = *(const short8*)&o[0];
  *(short8*)(d + 8) = *(const short8*)&o[8];
}

// counts[e] = sum of bf16 row e of hT [E][Nn]
__global__ __launch_bounds__(256) void counts_k(
    const ushort_t* __restrict__ hT, float* __restrict__ counts, int Nn) {
  const int e = blockIdx.x * 4 + (threadIdx.x >> 6);
  const int lane = threadIdx.x & 63;
  const ushort_t* row = hT + (size_t)e * Nn;
  float s = 0.f;
  for (int i = 0; i < Nn / 512; i++) {
    short8 v = *(const short8*)&row[i * 512 + lane * 8];
#pragma unroll
    for (int j = 0; j < 8; j++) s += bf2f(((ushort_t*)&v)[j]);
  }
#pragma unroll
  for (int off = 32; off > 0; off >>= 1) s += __shfl_down(s, off);
  if (lane == 0) counts[e] = s;
}

// out_bf16[i] = bf16(P[i]); P[i] = 0 (re-arm accumulator for next GEMM)
__global__ __launch_bounds__(256) void cast_zero_k(
    float* __restrict__ P, ushort_t* __restrict__ out) {
  const int i = (blockIdx.x * 256 + threadIdx.x) * 8;
  float4v a = *(const float4v*)&P[i];
  float4v b = *(const float4v*)&P[i + 4];
  ushort_t o[8];
  o[0] = f2bf(a.x); o[1] = f2bf(a.y); o[2] = f2bf(a.z); o[3] = f2bf(a.w);
  o[4] = f2bf(b.x); o[5] = f2bf(b.y); o[6] = f2bf(b.z); o[7] = f2bf(b.w);
  *(short8*)&out[i] = *(const short8*)o;
  float4v z = {0.f, 0.f, 0.f, 0.f};
  *(float4v*)&P[i] = z;
  *(float4v*)&P[i + 4] = z;
}

// P is x' in [128 d][Ncols m] layout. LayerNorm over d per column m,
// write xT[d][m] bf16 (same layout), re-zero P. Block: 64 cols, 4 row-quarters.
__global__ __launch_bounds__(256) void ln_cast_zero_k(
    float* __restrict__ P, const float* __restrict__ gamma,
    const float* __restrict__ beta, ushort_t* __restrict__ xT, int Ncols) {
  __shared__ float ssum[4][64], ssq[4][64];
  const int m = blockIdx.x * 64 + (threadIdx.x & 63);
  const int q = threadIdx.x >> 6;
  float s = 0.f, sq = 0.f;
  for (int d = q * 32; d < q * 32 + 32; d++) {
    float v = P[(size_t)d * Ncols + m];
    s += v; sq += v * v;
  }
  ssum[q][threadIdx.x & 63] = s;
  ssq[q][threadIdx.x & 63] = sq;
  __syncthreads();
  const int c = threadIdx.x & 63;
  float S = ssum[0][c] + ssum[1][c] + ssum[2][c] + ssum[3][c];
  float SQ = ssq[0][c] + ssq[1][c] + ssq[2][c] + ssq[3][c];
  const float mean = S * (1.f / 128.f);
  const float var = SQ * (1.f / 128.f) - mean * mean;
  const float inv = rsqrtf(var + 1e-5f);
  for (int d = q * 32; d < q * 32 + 32; d++) {
    size_t idx = (size_t)d * Ncols + m;
    float v = P[idx];
    xT[idx] = f2bf((v - mean) * inv * gamma[d] + beta[d]);
    P[idx] = 0.f;
  }
}

// max over hyperedges: P is sums [E][128] accumulated; pm[b][d] partial max
__global__ __launch_bounds__(128) void mm1_k(
    const float* __restrict__ P, const float* __restrict__ counts,
    float* __restrict__ pm) {
  const int d = threadIdx.x;
  float vmax = -3.4e38f;
  const int e0 = blockIdx.x * 128;
  for (int e = e0; e < e0 + 128; e++)
    vmax = fmaxf(vmax, P[(size_t)e * 128 + d] / counts[e]);
  pm[blockIdx.x * 128 + d] = vmax;
}

__global__ __launch_bounds__(128) void mm2_k(
    const float* __restrict__ pm, float* __restrict__ out, int B) {
  const int d = threadIdx.x;
  float v = -3.4e38f;
  for (int b = 0; b < B; b++) v = fmaxf(v, pm[b * 128 + d]);
  out[d] = v;
}

// ---------------------------------------------------------------------------
extern "C" void kernel_launch(void* const* d_in, const int* in_sizes, int n_in,
                              void* d_out, int out_size, void* d_ws,
                              size_t ws_size, hipStream_t stream) {
  const float* x0 = (const float*)d_in[0];
  const float* T = (const float*)d_in[1];
  const float* gamma = (const float*)d_in[2];
  const float* beta = (const float*)d_in[3];
  const int* h = (const int*)d_in[4];
  float* out = (float*)d_out;

  const int N = 8192, E = 4096, D = 128, K = 8192, S = 16;

  char* ws = (char*)d_ws;
  size_t off = 0;
  auto alloc = [&](size_t bytes) {
    char* p = ws + off;
    off += (bytes + 255) & ~(size_t)255;
    return p;
  };
  ushort_t* Tb = (ushort_t*)alloc((size_t)N * N * 2);  // T bf16
  ushort_t* Tt = (ushort_t*)alloc((size_t)N * N * 2);  // T^T bf16
  ushort_t* hT = (ushort_t*)alloc((size_t)E * N * 2);  // h^T bf16
  ushort_t* xT = (ushort_t*)alloc((size_t)D * N * 2);  // x^T bf16 [128][8192]
  ushort_t* tT = (ushort_t*)alloc((size_t)D * N * 2);  // t^T bf16 [128][8192]
  float* P = (float*)alloc((size_t)D * N * 4);         // fp32 accumulator 4 MB
  float* counts = (float*)alloc((size_t)E * 4);        // contiguous after P
  float* pm = (float*)alloc((size_t)32 * D * 4);
  (void)ws_size;

  // one memset arms P (4 MB) + counts; consumers re-zero P after reading
  hipMemsetAsync(P, 0, (size_t)D * N * 4 + 256 /*pad*/ + (size_t)E * 4, stream);

  dualcast_f32_k<<<dim3(N / 64, N / 64), 256, 0, stream>>>(T, Tb, Tt, N, N);
  dualcast_f32_k<<<dim3(N / 64, D / 64), 256, 0, stream>>>(x0, nullptr, xT, N, D);
  tcast_i32_k<<<dim3(N / 64, E / 64), 256, 0, stream>>>(h, hT, N, E);
  counts_k<<<E / 4, 256, 0, stream>>>(hT, counts, N);

  for (int layer = 0; layer < 3; layer++) {
    // tT[d][n] = sum_k xT[d][k] * Tb[n][k]   (t = T x, transposed space)
    gemm_tn<<<dim3(1, N / 128, S), 256, 0, stream>>>(xT, Tb, P, D, N, K, K / S);
    cast_zero_k<<<D * N / (256 * 8), 256, 0, stream>>>(P, tT);
    // x'T[d][m] = sum_k tT[d][k] * Tt[m][k]  (x' = T^T t, transposed space)
    gemm_tn<<<dim3(1, N / 128, S), 256, 0, stream>>>(tT, Tt, P, D, N, K, K / S);
    ln_cast_zero_k<<<N / 64, 256, 0, stream>>>(P, gamma, beta, xT, N);
  }
  // sums[e][d] = sum_n hT[e][n] * xT[d][n]
  gemm_tn<<<dim3(E / 128, 1, S), 256, 0, stream>>>(hT, xT, P, E, D, K, K / S);
  mm1_k<<<E / 128, 128, 0, stream>>>(P, counts, pm);
  mm2_k<<<1, 128, 0, stream>>>(pm, out, E / 128);
}

// Round 3
// 1007.356 us; speedup vs baseline: 1.0849x; 1.0849x over previous
//
#include <hip/hip_runtime.h>
#include <cstdint>
#include <cstddef>

typedef __attribute__((ext_vector_type(8))) short short8;
typedef __attribute__((ext_vector_type(4))) short short4v;
typedef __attribute__((ext_vector_type(4))) float float4v;
typedef __attribute__((ext_vector_type(4))) int int4v;
typedef unsigned short ushort_t;

__device__ __forceinline__ ushort_t f2bf(float f) {
  unsigned u = __builtin_bit_cast(unsigned, f);
  u = (u + 0x7FFFu + ((u >> 16) & 1u)) >> 16;  // RNE
  return (ushort_t)u;
}
__device__ __forceinline__ float bf2f(ushort_t h) {
  unsigned u = ((unsigned)h) << 16;
  return __builtin_bit_cast(float, u);
}

__device__ __forceinline__ void gld_lds16(const void* g, void* l) {
  __builtin_amdgcn_global_load_lds(
      (const __attribute__((address_space(1))) void*)g,
      (__attribute__((address_space(3))) void*)l, 16, 0, 0);
}

// ---------------------------------------------------------------------------
// TN GEMM, plain-store split-K: P[z][m][n] = sum_{k in slice z} A[m][k]*B[n][k]
// A:[M][K] bf16, B:[N][K] bf16. Tile 128x128, BK=64.
// K=8192 -> 128 k-tiles split over 12 z-slices as 8x11 + 4x10.
// grid (M/128, N/128, 12), block 256 (4 waves, 2x2 of 64x64).
// ---------------------------------------------------------------------------
__global__ __launch_bounds__(256, 2) void gemm_tn(
    const ushort_t* __restrict__ A, const ushort_t* __restrict__ B,
    float* __restrict__ P, int M, int N, int K) {
  __shared__ ushort_t As[128 * 64];
  __shared__ ushort_t Bs[128 * 64];
  const int tid = threadIdx.x;
  const int lane = tid & 63;
  const int wave = tid >> 6;
  const int wm = (wave & 1) * 64;
  const int wn = (wave >> 1) * 64;
  const int m0 = blockIdx.x * 128;
  const int n0 = blockIdx.y * 128;
  int t0, tl;
  if (blockIdx.z < 8) { t0 = blockIdx.z * 11; tl = 11; }
  else { t0 = 88 + (blockIdx.z - 8) * 10; tl = 10; }
  float* __restrict__ Pc = P + (size_t)blockIdx.z * M * N;

  float4v acc[4][4] = {};

  for (int t = t0; t < t0 + tl; t++) {
    const ushort_t* Ag = A + (size_t)m0 * K + t * 64;
    const ushort_t* Bg = B + (size_t)n0 * K + t * 64;
#pragma unroll
    for (int i = 0; i < 4; i++) {
      int f = i * 4096 + tid * 16;  // flat byte in 16KB tile
      int r = f >> 7;               // row (128B per row = 64 bf16)
      int cb = f & 127;             // byte within row
      gld_lds16((const char*)(Ag + (size_t)r * K) + cb, (char*)As + f);
      gld_lds16((const char*)(Bg + (size_t)r * K) + cb, (char*)Bs + f);
    }
    __syncthreads();
#pragma unroll
    for (int ks = 0; ks < 64; ks += 32) {
      short8 af[4], bfr[4];
      const int kr = ks + (lane >> 4) * 8;
      const int l15 = lane & 15;
#pragma unroll
      for (int im = 0; im < 4; im++)
        af[im] = *(const short8*)&As[(wm + im * 16 + l15) * 64 + kr];
#pragma unroll
      for (int in = 0; in < 4; in++)
        bfr[in] = *(const short8*)&Bs[(wn + in * 16 + l15) * 64 + kr];
#pragma unroll
      for (int im = 0; im < 4; im++)
#pragma unroll
        for (int in = 0; in < 4; in++)
          acc[im][in] = __builtin_amdgcn_mfma_f32_16x16x32_bf16(
              af[im], bfr[in], acc[im][in], 0, 0, 0);
    }
    __syncthreads();
  }
  // C/D layout: col(n) = lane&15, row(m) = (lane>>4)*4 + reg  [m89/m91]
  const int cn = lane & 15;
  const int cr = (lane >> 4) * 4;
#pragma unroll
  for (int im = 0; im < 4; im++)
#pragma unroll
    for (int in = 0; in < 4; in++)
#pragma unroll
      for (int r = 0; r < 4; r++) {
        int m = wm + im * 16 + cr + r;
        int n = wn + in * 16 + cn;
        Pc[(size_t)(m0 + m) * N + (n0 + n)] = acc[im][in][r];
      }
}

// ---------------------------------------------------------------------------
// fp32 [R][C] -> bf16 transposed [C][R] (+ optional non-transposed copy).
// fp32 LDS tile, stride 65 dwords: all LDS accesses <=2-way (free).
// ---------------------------------------------------------------------------
__global__ __launch_bounds__(256) void dualcast_f32_k(
    const float* __restrict__ src, ushort_t* __restrict__ dstN,
    ushort_t* __restrict__ dstT, int R, int C) {
  __shared__ float tile[64][65];
  const int r0 = blockIdx.x * 64, c0 = blockIdx.y * 64;
  const int tr = threadIdx.x >> 2, cs = (threadIdx.x & 3) * 16;
  const float* s = src + (size_t)(r0 + tr) * C + c0 + cs;
  float v[16];
#pragma unroll
  for (int j = 0; j < 16; j += 4) {
    float4v t4 = __builtin_nontemporal_load((const float4v*)(s + j));
    v[j] = t4.x; v[j + 1] = t4.y; v[j + 2] = t4.z; v[j + 3] = t4.w;
  }
  if (dstN) {
    ushort_t o[16];
#pragma unroll
    for (int j = 0; j < 16; j++) o[j] = f2bf(v[j]);
    ushort_t* d = dstN + (size_t)(r0 + tr) * C + c0 + cs;
    *(short8*)d = *(const short8*)&o[0];
    *(short8*)(d + 8) = *(const short8*)&o[8];
  }
#pragma unroll
  for (int j = 0; j < 16; j++) tile[tr][cs + j] = v[j];
  __syncthreads();
  const int tc = threadIdx.x >> 2, rs = (threadIdx.x & 3) * 16;
  ushort_t o[16];
#pragma unroll
  for (int j = 0; j < 16; j++) o[j] = f2bf(tile[rs + j][tc]);
  ushort_t* d = dstT + (size_t)(c0 + tc) * R + r0 + rs;
  *(short8*)d = *(const short8*)&o[0];
  *(short8*)(d + 8) = *(const short8*)&o[8];
}

// int32 [R][C] -> bf16 (x>0 ? 1 : 0) transposed [C][R]
__global__ __launch_bounds__(256) void tcast_i32_k(
    const int* __restrict__ src, ushort_t* __restrict__ dstT, int R, int C) {
  __shared__ float tile[64][65];
  const int r0 = blockIdx.x * 64, c0 = blockIdx.y * 64;
  const int tr = threadIdx.x >> 2, cs = (threadIdx.x & 3) * 16;
  const int* s = src + (size_t)(r0 + tr) * C + c0 + cs;
#pragma unroll
  for (int j = 0; j < 16; j += 4) {
    int4v t4 = __builtin_nontemporal_load((const int4v*)(s + j));
    tile[tr][cs + j] = t4.x > 0 ? 1.f : 0.f;
    tile[tr][cs + j + 1] = t4.y > 0 ? 1.f : 0.f;
    tile[tr][cs + j + 2] = t4.z > 0 ? 1.f : 0.f;
    tile[tr][cs + j + 3] = t4.w > 0 ? 1.f : 0.f;
  }
  __syncthreads();
  const int tc = threadIdx.x >> 2, rs = (threadIdx.x & 3) * 16;
  ushort_t o[16];
#pragma unroll
  for (int j = 0; j < 16; j++) o[j] = f2bf(tile[rs + j][tc]);
  ushort_t* d = dstT + (size_t)(c0 + tc) * R + r0 + rs;
  *(short8*)d = *(const short8*)&o[0];
  *(short8*)(d + 8) = *(const short8*)&o[8];
}

// counts[e] = sum of bf16 row e of hT [E][Nn]
__global__ __launch_bounds__(256) void counts_k(
    const ushort_t* __restrict__ hT, float* __restrict__ counts, int Nn) {
  const int e = blockIdx.x * 4 + (threadIdx.x >> 6);
  const int lane = threadIdx.x & 63;
  const ushort_t* row = hT + (size_t)e * Nn;
  float s = 0.f;
  for (int i = 0; i < Nn / 512; i++) {
    short8 v = *(const short8*)&row[i * 512 + lane * 8];
#pragma unroll
    for (int j = 0; j < 8; j++) s += bf2f(((ushort_t*)&v)[j]);
  }
#pragma unroll
  for (int off = 32; off > 0; off >>= 1) s += __shfl_down(s, off);
  if (lane == 0) counts[e] = s;
}

// out_bf16[i] = bf16( sum_s P[s][i] ), S=12 slices
__global__ __launch_bounds__(256) void cast_k(
    const float* __restrict__ P, ushort_t* __restrict__ out, int MN) {
  const int i = (blockIdx.x * 256 + threadIdx.x) * 8;
  float4v a = {0.f, 0.f, 0.f, 0.f}, b = {0.f, 0.f, 0.f, 0.f};
  for (int sp = 0; sp < 12; sp++) {
    a += *(const float4v*)&P[(size_t)sp * MN + i];
    b += *(const float4v*)&P[(size_t)sp * MN + i + 4];
  }
  ushort_t o[8];
  o[0] = f2bf(a.x); o[1] = f2bf(a.y); o[2] = f2bf(a.z); o[3] = f2bf(a.w);
  o[4] = f2bf(b.x); o[5] = f2bf(b.y); o[6] = f2bf(b.z); o[7] = f2bf(b.w);
  *(short8*)&out[i] = *(const short8*)o;
}

// P[s][d][m]: sum 12 slices, LayerNorm over d per column m, write xT[d][m] bf16.
// block: 32 cols x 8 d-groups of 16. grid Ncols/32.
__global__ __launch_bounds__(256) void ln_cast_k(
    const float* __restrict__ P, const float* __restrict__ gamma,
    const float* __restrict__ beta, ushort_t* __restrict__ xT, int Ncols) {
  __shared__ float ssum[8][32], ssq[8][32];
  const int c = threadIdx.x & 31;
  const int q = threadIdx.x >> 5;
  const int m = blockIdx.x * 32 + c;
  const size_t DN = (size_t)128 * Ncols;
  float vloc[16];
  float s = 0.f, sq = 0.f;
#pragma unroll
  for (int j = 0; j < 16; j++) {
    const int d = q * 16 + j;
    float v = 0.f;
    for (int sp = 0; sp < 12; sp++)
      v += P[(size_t)sp * DN + (size_t)d * Ncols + m];
    vloc[j] = v; s += v; sq += v * v;
  }
  ssum[q][c] = s;
  ssq[q][c] = sq;
  __syncthreads();
  float S = 0.f, SQ = 0.f;
#pragma unroll
  for (int r = 0; r < 8; r++) { S += ssum[r][c]; SQ += ssq[r][c]; }
  const float mean = S * (1.f / 128.f);
  const float var = SQ * (1.f / 128.f) - mean * mean;
  const float inv = rsqrtf(var + 1e-5f);
#pragma unroll
  for (int j = 0; j < 16; j++) {
    const int d = q * 16 + j;
    xT[(size_t)d * Ncols + m] = f2bf((vloc[j] - mean) * inv * gamma[d] + beta[d]);
  }
}

// P[s][e][128]: sum 12 slices, divide by counts[e], partial max over 16 e/block
__global__ __launch_bounds__(256) void mm1_k(
    const float* __restrict__ P, const float* __restrict__ counts,
    float* __restrict__ pm, int EMN) {
  __shared__ float4v red[8][32];
  const int el = threadIdx.x >> 5;
  const int l32 = threadIdx.x & 31;
  const int e0 = blockIdx.x * 16;
  float4v vmax = {-3.4e38f, -3.4e38f, -3.4e38f, -3.4e38f};
  for (int ee = el; ee < 16; ee += 8) {
    const int e = e0 + ee;
    float4v s = {0.f, 0.f, 0.f, 0.f};
    for (int sp = 0; sp < 12; sp++)
      s += *(const float4v*)&P[(size_t)sp * EMN + (size_t)e * 128 + l32 * 4];
    const float inv = 1.f / counts[e];
    s *= inv;
    vmax.x = fmaxf(vmax.x, s.x); vmax.y = fmaxf(vmax.y, s.y);
    vmax.z = fmaxf(vmax.z, s.z); vmax.w = fmaxf(vmax.w, s.w);
  }
  red[el][l32] = vmax;
  __syncthreads();
  if (el == 0) {
    float4v m = red[0][l32];
#pragma unroll
    for (int r = 1; r < 8; r++) {
      float4v t = red[r][l32];
      m.x = fmaxf(m.x, t.x); m.y = fmaxf(m.y, t.y);
      m.z = fmaxf(m.z, t.z); m.w = fmaxf(m.w, t.w);
    }
    *(float4v*)&pm[(size_t)blockIdx.x * 128 + l32 * 4] = m;
  }
}

__global__ __launch_bounds__(128) void mm2_k(
    const float* __restrict__ pm, float* __restrict__ out, int B) {
  const int d = threadIdx.x;
  float v = -3.4e38f;
  for (int b = 0; b < B; b++) v = fmaxf(v, pm[b * 128 + d]);
  out[d] = v;
}

// ---------------------------------------------------------------------------
extern "C" void kernel_launch(void* const* d_in, const int* in_sizes, int n_in,
                              void* d_out, int out_size, void* d_ws,
                              size_t ws_size, hipStream_t stream) {
  const float* x0 = (const float*)d_in[0];
  const float* T = (const float*)d_in[1];
  const float* gamma = (const float*)d_in[2];
  const float* beta = (const float*)d_in[3];
  const int* h = (const int*)d_in[4];
  float* out = (float*)d_out;

  const int N = 8192, E = 4096, D = 128, K = 8192, S = 12;

  char* ws = (char*)d_ws;
  size_t off = 0;
  auto alloc = [&](size_t bytes) {
    char* p = ws + off;
    off += (bytes + 255) & ~(size_t)255;
    return p;
  };
  ushort_t* Tb = (ushort_t*)alloc((size_t)N * N * 2);  // T bf16
  ushort_t* Tt = (ushort_t*)alloc((size_t)N * N * 2);  // T^T bf16
  ushort_t* hT = (ushort_t*)alloc((size_t)E * N * 2);  // h^T bf16
  ushort_t* xT = (ushort_t*)alloc((size_t)D * N * 2);  // x^T bf16 [128][8192]
  ushort_t* tT = (ushort_t*)alloc((size_t)D * N * 2);  // t^T bf16 [128][8192]
  float* P = (float*)alloc((size_t)S * D * N * 4);     // split-K partials 48MB
  float* counts = (float*)alloc((size_t)E * 4);
  float* pm = (float*)alloc((size_t)256 * D * 4);
  (void)ws_size;

  dualcast_f32_k<<<dim3(N / 64, N / 64), 256, 0, stream>>>(T, Tb, Tt, N, N);
  dualcast_f32_k<<<dim3(N / 64, D / 64), 256, 0, stream>>>(x0, nullptr, xT, N, D);
  tcast_i32_k<<<dim3(N / 64, E / 64), 256, 0, stream>>>(h, hT, N, E);
  counts_k<<<E / 4, 256, 0, stream>>>(hT, counts, N);

  for (int layer = 0; layer < 3; layer++) {
    // tT[d][n] = sum_k xT[d][k] * Tb[n][k]   (t = T x, transposed space)
    gemm_tn<<<dim3(1, N / 128, S), 256, 0, stream>>>(xT, Tb, P, D, N, K);
    cast_k<<<D * N / (256 * 8), 256, 0, stream>>>(P, tT, D * N);
    // x'T[d][m] = sum_k tT[d][k] * Tt[m][k]  (x' = T^T t, transposed space)
    gemm_tn<<<dim3(1, N / 128, S), 256, 0, stream>>>(tT, Tt, P, D, N, K);
    ln_cast_k<<<N / 32, 256, 0, stream>>>(P, gamma, beta, xT, N);
  }
  // sums[e][d] = sum_n hT[e][n] * xT[d][n]
  gemm_tn<<<dim3(E / 128, 1, S), 256, 0, stream>>>(hT, xT, P, E, D, K);
  mm1_k<<<E / 16, 256, 0, stream>>>(P, counts, pm, E * D);
  mm2_k<<<1, 128, 0, stream>>>(pm, out, E / 16);
}

// Round 4
// 956.796 us; speedup vs baseline: 1.1423x; 1.0528x over previous
//
#include <hip/hip_runtime.h>
#include <cstdint>
#include <cstddef>

typedef __attribute__((ext_vector_type(8))) short short8;
typedef __attribute__((ext_vector_type(4))) short short4v;
typedef __attribute__((ext_vector_type(4))) float float4v;
typedef __attribute__((ext_vector_type(4))) int int4v;
typedef unsigned short ushort_t;

__device__ __forceinline__ ushort_t f2bf(float f) {
  unsigned u = __builtin_bit_cast(unsigned, f);
  u = (u + 0x7FFFu + ((u >> 16) & 1u)) >> 16;  // RNE
  return (ushort_t)u;
}
__device__ __forceinline__ float bf2f(ushort_t h) {
  unsigned u = ((unsigned)h) << 16;
  return __builtin_bit_cast(float, u);
}

__device__ __forceinline__ void gld_lds16(const void* g, void* l) {
  __builtin_amdgcn_global_load_lds(
      (const __attribute__((address_space(1))) void*)g,
      (__attribute__((address_space(3))) void*)l, 16, 0, 0);
}

// ---------------------------------------------------------------------------
// TN GEMM, plain-store split-K: P[z][m][n] = sum_{k in slice z} A[m][k]*B[n][k]
// A:[M][K] bf16, B:[N][K] bf16. Tile 128x128, BK=64.
// K=8192 -> 128 k-tiles split over 12 z-slices as 8x11 + 4x10.
// grid (M/128, N/128, 12), block 256 (4 waves, 2x2 of 64x64).
// __launch_bounds__(256,3): cap VGPR ~170 so 3 blocks/CU co-reside (m97 regime)
// ---------------------------------------------------------------------------
__global__ __launch_bounds__(256, 3) void gemm_tn(
    const ushort_t* __restrict__ A, const ushort_t* __restrict__ B,
    float* __restrict__ P, int M, int N, int K) {
  __shared__ ushort_t As[128 * 64];
  __shared__ ushort_t Bs[128 * 64];
  const int tid = threadIdx.x;
  const int lane = tid & 63;
  const int wave = tid >> 6;
  const int wm = (wave & 1) * 64;
  const int wn = (wave >> 1) * 64;
  const int m0 = blockIdx.x * 128;
  const int n0 = blockIdx.y * 128;
  int t0, tl;
  if (blockIdx.z < 8) { t0 = blockIdx.z * 11; tl = 11; }
  else { t0 = 88 + (blockIdx.z - 8) * 10; tl = 10; }
  float* __restrict__ Pc = P + (size_t)blockIdx.z * M * N;

  float4v acc[4][4] = {};

  for (int t = t0; t < t0 + tl; t++) {
    const ushort_t* Ag = A + (size_t)m0 * K + t * 64;
    const ushort_t* Bg = B + (size_t)n0 * K + t * 64;
#pragma unroll
    for (int i = 0; i < 4; i++) {
      int f = i * 4096 + tid * 16;  // flat byte in 16KB tile
      int r = f >> 7;               // row (128B per row = 64 bf16)
      int cb = f & 127;             // byte within row
      gld_lds16((const char*)(Ag + (size_t)r * K) + cb, (char*)As + f);
      gld_lds16((const char*)(Bg + (size_t)r * K) + cb, (char*)Bs + f);
    }
    __syncthreads();
#pragma unroll
    for (int ks = 0; ks < 64; ks += 32) {
      short8 af[4], bfr[4];
      const int kr = ks + (lane >> 4) * 8;
      const int l15 = lane & 15;
#pragma unroll
      for (int im = 0; im < 4; im++)
        af[im] = *(const short8*)&As[(wm + im * 16 + l15) * 64 + kr];
#pragma unroll
      for (int in = 0; in < 4; in++)
        bfr[in] = *(const short8*)&Bs[(wn + in * 16 + l15) * 64 + kr];
#pragma unroll
      for (int im = 0; im < 4; im++)
#pragma unroll
        for (int in = 0; in < 4; in++)
          acc[im][in] = __builtin_amdgcn_mfma_f32_16x16x32_bf16(
              af[im], bfr[in], acc[im][in], 0, 0, 0);
    }
    __syncthreads();
  }
  // C/D layout: col(n) = lane&15, row(m) = (lane>>4)*4 + reg  [m89/m91]
  const int cn = lane & 15;
  const int cr = (lane >> 4) * 4;
#pragma unroll
  for (int im = 0; im < 4; im++)
#pragma unroll
    for (int in = 0; in < 4; in++)
#pragma unroll
      for (int r = 0; r < 4; r++) {
        int m = wm + im * 16 + cr + r;
        int n = wn + in * 16 + cn;
        Pc[(size_t)(m0 + m) * N + (n0 + n)] = acc[im][in][r];
      }
}

// ---------------------------------------------------------------------------
// fp32 [R][C] -> bf16 transposed [C][R] (+ optional non-transposed copy).
// grid.x = COLUMN tile (consecutive blocks sweep along rows -> sequential
// HBM read stream); fp32 LDS tile stride 65: all accesses <=2-way.
// ---------------------------------------------------------------------------
__global__ __launch_bounds__(256) void dualcast_f32_k(
    const float* __restrict__ src, ushort_t* __restrict__ dstN,
    ushort_t* __restrict__ dstT, int R, int C) {
  __shared__ float tile[64][65];
  const int c0 = blockIdx.x * 64, r0 = blockIdx.y * 64;
  const int tr = threadIdx.x >> 2, cs = (threadIdx.x & 3) * 16;
  const float* s = src + (size_t)(r0 + tr) * C + c0 + cs;
  float v[16];
#pragma unroll
  for (int j = 0; j < 16; j += 4) {
    float4v t4 = *(const float4v*)(s + j);
    v[j] = t4.x; v[j + 1] = t4.y; v[j + 2] = t4.z; v[j + 3] = t4.w;
  }
  if (dstN) {
    ushort_t o[16];
#pragma unroll
    for (int j = 0; j < 16; j++) o[j] = f2bf(v[j]);
    ushort_t* d = dstN + (size_t)(r0 + tr) * C + c0 + cs;
    *(short8*)d = *(const short8*)&o[0];
    *(short8*)(d + 8) = *(const short8*)&o[8];
  }
#pragma unroll
  for (int j = 0; j < 16; j++) tile[tr][cs + j] = v[j];
  __syncthreads();
  const int tc = threadIdx.x >> 2, rs = (threadIdx.x & 3) * 16;
  ushort_t o[16];
#pragma unroll
  for (int j = 0; j < 16; j++) o[j] = f2bf(tile[rs + j][tc]);
  ushort_t* d = dstT + (size_t)(c0 + tc) * R + r0 + rs;
  *(short8*)d = *(const short8*)&o[0];
  *(short8*)(d + 8) = *(const short8*)&o[8];
}

// int32 [R][C] -> bf16 (x>0 ? 1 : 0) transposed [C][R]; grid.x = column tile
__global__ __launch_bounds__(256) void tcast_i32_k(
    const int* __restrict__ src, ushort_t* __restrict__ dstT, int R, int C) {
  __shared__ float tile[64][65];
  const int c0 = blockIdx.x * 64, r0 = blockIdx.y * 64;
  const int tr = threadIdx.x >> 2, cs = (threadIdx.x & 3) * 16;
  const int* s = src + (size_t)(r0 + tr) * C + c0 + cs;
#pragma unroll
  for (int j = 0; j < 16; j += 4) {
    int4v t4 = *(const int4v*)(s + j);
    tile[tr][cs + j] = t4.x > 0 ? 1.f : 0.f;
    tile[tr][cs + j + 1] = t4.y > 0 ? 1.f : 0.f;
    tile[tr][cs + j + 2] = t4.z > 0 ? 1.f : 0.f;
    tile[tr][cs + j + 3] = t4.w > 0 ? 1.f : 0.f;
  }
  __syncthreads();
  const int tc = threadIdx.x >> 2, rs = (threadIdx.x & 3) * 16;
  ushort_t o[16];
#pragma unroll
  for (int j = 0; j < 16; j++) o[j] = f2bf(tile[rs + j][tc]);
  ushort_t* d = dstT + (size_t)(c0 + tc) * R + r0 + rs;
  *(short8*)d = *(const short8*)&o[0];
  *(short8*)(d + 8) = *(const short8*)&o[8];
}

// counts[e] = sum of bf16 row e of hT [E][Nn]
__global__ __launch_bounds__(256) void counts_k(
    const ushort_t* __restrict__ hT, float* __restrict__ counts, int Nn) {
  const int e = blockIdx.x * 4 + (threadIdx.x >> 6);
  const int lane = threadIdx.x & 63;
  const ushort_t* row = hT + (size_t)e * Nn;
  float s = 0.f;
  for (int i = 0; i < Nn / 512; i++) {
    short8 v = *(const short8*)&row[i * 512 + lane * 8];
#pragma unroll
    for (int j = 0; j < 8; j++) s += bf2f(((ushort_t*)&v)[j]);
  }
#pragma unroll
  for (int off = 32; off > 0; off >>= 1) s += __shfl_down(s, off);
  if (lane == 0) counts[e] = s;
}

// out_bf16[i] = bf16( sum_s P[s][i] ), S=12 slices
__global__ __launch_bounds__(256) void cast_k(
    const float* __restrict__ P, ushort_t* __restrict__ out, int MN) {
  const int i = (blockIdx.x * 256 + threadIdx.x) * 8;
  float4v a = {0.f, 0.f, 0.f, 0.f}, b = {0.f, 0.f, 0.f, 0.f};
  for (int sp = 0; sp < 12; sp++) {
    a += *(const float4v*)&P[(size_t)sp * MN + i];
    b += *(const float4v*)&P[(size_t)sp * MN + i + 4];
  }
  ushort_t o[8];
  o[0] = f2bf(a.x); o[1] = f2bf(a.y); o[2] = f2bf(a.z); o[3] = f2bf(a.w);
  o[4] = f2bf(b.x); o[5] = f2bf(b.y); o[6] = f2bf(b.z); o[7] = f2bf(b.w);
  *(short8*)&out[i] = *(const short8*)o;
}

// P[s][d][m]: sum 12 slices, LayerNorm over d per column m, write xT[d][m] bf16.
// block: 32 cols x 8 d-groups of 16. grid Ncols/32.
__global__ __launch_bounds__(256) void ln_cast_k(
    const float* __restrict__ P, const float* __restrict__ gamma,
    const float* __restrict__ beta, ushort_t* __restrict__ xT, int Ncols) {
  __shared__ float ssum[8][32], ssq[8][32];
  const int c = threadIdx.x & 31;
  const int q = threadIdx.x >> 5;
  const int m = blockIdx.x * 32 + c;
  const size_t DN = (size_t)128 * Ncols;
  float vloc[16];
  float s = 0.f, sq = 0.f;
#pragma unroll
  for (int j = 0; j < 16; j++) {
    const int d = q * 16 + j;
    float v = 0.f;
    for (int sp = 0; sp < 12; sp++)
      v += P[(size_t)sp * DN + (size_t)d * Ncols + m];
    vloc[j] = v; s += v; sq += v * v;
  }
  ssum[q][c] = s;
  ssq[q][c] = sq;
  __syncthreads();
  float S = 0.f, SQ = 0.f;
#pragma unroll
  for (int r = 0; r < 8; r++) { S += ssum[r][c]; SQ += ssq[r][c]; }
  const float mean = S * (1.f / 128.f);
  const float var = SQ * (1.f / 128.f) - mean * mean;
  const float inv = rsqrtf(var + 1e-5f);
#pragma unroll
  for (int j = 0; j < 16; j++) {
    const int d = q * 16 + j;
    xT[(size_t)d * Ncols + m] = f2bf((vloc[j] - mean) * inv * gamma[d] + beta[d]);
  }
}

// P[s][e][128]: sum 12 slices, divide by counts[e], partial max over 16 e/block
__global__ __launch_bounds__(256) void mm1_k(
    const float* __restrict__ P, const float* __restrict__ counts,
    float* __restrict__ pm, int EMN) {
  __shared__ float4v red[8][32];
  const int el = threadIdx.x >> 5;
  const int l32 = threadIdx.x & 31;
  const int e0 = blockIdx.x * 16;
  float4v vmax = {-3.4e38f, -3.4e38f, -3.4e38f, -3.4e38f};
  for (int ee = el; ee < 16; ee += 8) {
    const int e = e0 + ee;
    float4v s = {0.f, 0.f, 0.f, 0.f};
    for (int sp = 0; sp < 12; sp++)
      s += *(const float4v*)&P[(size_t)sp * EMN + (size_t)e * 128 + l32 * 4];
    const float inv = 1.f / counts[e];
    s *= inv;
    vmax.x = fmaxf(vmax.x, s.x); vmax.y = fmaxf(vmax.y, s.y);
    vmax.z = fmaxf(vmax.z, s.z); vmax.w = fmaxf(vmax.w, s.w);
  }
  red[el][l32] = vmax;
  __syncthreads();
  if (el == 0) {
    float4v m = red[0][l32];
#pragma unroll
    for (int r = 1; r < 8; r++) {
      float4v t = red[r][l32];
      m.x = fmaxf(m.x, t.x); m.y = fmaxf(m.y, t.y);
      m.z = fmaxf(m.z, t.z); m.w = fmaxf(m.w, t.w);
    }
    *(float4v*)&pm[(size_t)blockIdx.x * 128 + l32 * 4] = m;
  }
}

__global__ __launch_bounds__(128) void mm2_k(
    const float* __restrict__ pm, float* __restrict__ out, int B) {
  const int d = threadIdx.x;
  float v = -3.4e38f;
  for (int b = 0; b < B; b++) v = fmaxf(v, pm[b * 128 + d]);
  out[d] = v;
}

// ---------------------------------------------------------------------------
extern "C" void kernel_launch(void* const* d_in, const int* in_sizes, int n_in,
                              void* d_out, int out_size, void* d_ws,
                              size_t ws_size, hipStream_t stream) {
  const float* x0 = (const float*)d_in[0];
  const float* T = (const float*)d_in[1];
  const float* gamma = (const float*)d_in[2];
  const float* beta = (const float*)d_in[3];
  const int* h = (const int*)d_in[4];
  float* out = (float*)d_out;

  const int N = 8192, E = 4096, D = 128, K = 8192, S = 12;

  char* ws = (char*)d_ws;
  size_t off = 0;
  auto alloc = [&](size_t bytes) {
    char* p = ws + off;
    off += (bytes + 255) & ~(size_t)255;
    return p;
  };
  ushort_t* Tb = (ushort_t*)alloc((size_t)N * N * 2);  // T bf16
  ushort_t* Tt = (ushort_t*)alloc((size_t)N * N * 2);  // T^T bf16
  ushort_t* hT = (ushort_t*)alloc((size_t)E * N * 2);  // h^T bf16
  ushort_t* xT = (ushort_t*)alloc((size_t)D * N * 2);  // x^T bf16 [128][8192]
  ushort_t* tT = (ushort_t*)alloc((size_t)D * N * 2);  // t^T bf16 [128][8192]
  float* P = (float*)alloc((size_t)S * D * N * 4);     // split-K partials 48MB
  float* counts = (float*)alloc((size_t)E * 4);
  float* pm = (float*)alloc((size_t)256 * D * 4);
  (void)ws_size;

  // grid.x = column tiles (horizontal sweep), grid.y = row tiles
  dualcast_f32_k<<<dim3(N / 64, N / 64), 256, 0, stream>>>(T, Tb, Tt, N, N);
  dualcast_f32_k<<<dim3(D / 64, N / 64), 256, 0, stream>>>(x0, nullptr, xT, N, D);
  tcast_i32_k<<<dim3(E / 64, N / 64), 256, 0, stream>>>(h, hT, N, E);
  counts_k<<<E / 4, 256, 0, stream>>>(hT, counts, N);

  for (int layer = 0; layer < 3; layer++) {
    // tT[d][n] = sum_k xT[d][k] * Tb[n][k]   (t = T x, transposed space)
    gemm_tn<<<dim3(1, N / 128, S), 256, 0, stream>>>(xT, Tb, P, D, N, K);
    cast_k<<<D * N / (256 * 8), 256, 0, stream>>>(P, tT, D * N);
    // x'T[d][m] = sum_k tT[d][k] * Tt[m][k]  (x' = T^T t, transposed space)
    gemm_tn<<<dim3(1, N / 128, S), 256, 0, stream>>>(tT, Tt, P, D, N, K);
    ln_cast_k<<<N / 32, 256, 0, stream>>>(P, gamma, beta, xT, N);
  }
  // sums[e][d] = sum_n hT[e][n] * xT[d][n]
  gemm_tn<<<dim3(E / 128, 1, S), 256, 0, stream>>>(hT, xT, P, E, D, K);
  mm1_k<<<E / 16, 256, 0, stream>>>(P, counts, pm, E * D);
  mm2_k<<<1, 128, 0, stream>>>(pm, out, E / 16);
}